// Round 8
// baseline (127.073 us; speedup 1.0000x reference)
//
#include <hip/hip_runtime.h>
#include <math.h>

#define DD 1024
#define BB 16
#define GAMMA_C 0.1f

__device__ __forceinline__ float wred_sum(float v){
  #pragma unroll
  for (int o = 32; o > 0; o >>= 1) v += __shfl_xor(v, o, 64);
  return v;
}
__device__ __forceinline__ float wred_max(float v){
  #pragma unroll
  for (int o = 32; o > 0; o >>= 1) v = fmaxf(v, __shfl_xor(v, o, 64));
  return v;
}
__device__ __forceinline__ float wred_min(float v){
  #pragma unroll
  for (int o = 32; o > 0; o >>= 1) v = fminf(v, __shfl_xor(v, o, 64));
  return v;
}

// ============== single kernel: block = (batch row b, 256-col chunk qc) ======
// 64 blocks x 256 threads. Everything block-local; one plain store per (b,i).
__global__ __launch_bounds__(256) void mega(
    const float* __restrict__ x, const float* __restrict__ beta,
    const float* __restrict__ W, const float* __restrict__ bl,
    const float* __restrict__ proj,
    const float* __restrict__ wq, const float* __restrict__ wk,
    const float* __restrict__ wv, const float* __restrict__ wo,
    const float* __restrict__ proto,
    float* __restrict__ out){
  __shared__ float xs[DD];
  __shared__ float w_s[40];
  __shared__ float rmx4[4], rmn4[4];
  __shared__ int   cnti[64];
  __shared__ float sumf[64];
  __shared__ float ybS[64], lnnS[64], nfS[64];
  __shared__ float csS[2][64];
  __shared__ float4 binA[64];   // (yb, nf, c40, c50)
  __shared__ float2 binB[64];   // (c41, c51)
  __shared__ float coeff[32];
  __shared__ float linS[256];

  int tid = threadIdx.x, wid = tid >> 6, lane = tid & 63;
  int blk = blockIdx.x;
  int b = blk >> 2, qc = blk & 3;

  // ---- stage row, zero hist, wave0 softmax(beta), row min/max ----
  float4 xv4 = ((const float4*)(x + b*DD))[tid];
  ((float4*)xs)[tid] = xv4;
  if (tid < 64){ cnti[tid] = 0; sumf[tid] = 0.f; }
  if (tid < 64){
    float bb = (tid < 40) ? beta[tid] : -3.0e38f;
    float m = wred_max(bb);
    float e = (tid < 40) ? __expf(bb - m) : 0.f;
    float ssum = wred_sum(e);
    if (tid < 40) w_s[tid] = e / ssum;
  }
  float lmx = fmaxf(fmaxf(xv4.x, xv4.y), fmaxf(xv4.z, xv4.w));
  float lmn = fminf(fminf(xv4.x, xv4.y), fminf(xv4.z, xv4.w));
  lmx = wred_max(lmx); lmn = wred_min(lmn);
  if (lane == 0){ rmx4[wid] = lmx; rmn4[wid] = lmn; }
  // attn scalars (per wave, no barrier needed)
  float tq = (lane < 8) ? wq[lane]*wk[lane] : 0.f;
  float tv = (lane < 8) ? wv[lane]*wo[lane] : 0.f;
  float qk = wred_sum(tq);
  float vo = wred_sum(tv);
  __syncthreads();
  float MX = fmaxf(fmaxf(rmx4[0], rmx4[1]), fmaxf(rmx4[2], rmx4[3]));
  float MN = fminf(fminf(rmn4[0], rmn4[1]), fminf(rmn4[2], rmn4[3]));
  float invw = 64.f / (MX - MN);

  // ---- histogram ----
  {
    float vs[4] = {xv4.x, xv4.y, xv4.z, xv4.w};
    #pragma unroll
    for (int k = 0; k < 4; k++){
      int g = min((int)((vs[k] - MN) * invw), 63);
      atomicAdd(&cnti[g], 1);
      atomicAdd(&sumf[g], vs[k]);
    }
  }
  __syncthreads();
  if (tid < 64){
    int n = cnti[tid];
    float nf = (float)n;
    ybS[tid]  = n ? sumf[tid] / nf : MN + (tid + 0.5f) / invw;
    nfS[tid]  = nf;
    lnnS[tid] = n ? __logf(nf) : -1e30f;
  }
  __syncthreads();

  // ---- binned Sinkhorn, 5 iterations, waves 0 (tau=0.5) and 1 (tau=1) ----
  {
    int tau = wid;
    bool act = (wid < 2);
    float it = (tau == 0) ? 2.f : 1.f;
    float ybg  = act ? ybS[lane]  : 0.f;
    float lnng = act ? lnnS[lane] : 0.f;
    float qg = it * ybg * ybg;
    float kg = 2.f * it * ybg;
    float V = 0.f, C4 = 0.f;
    for (int iter = 0; iter < 5; iter++){
      float c = lnng - qg - V;
      if (iter == 4) C4 = c;
      if (act) csS[tau][lane] = c;
      __syncthreads();
      float U = 0.f;
      if (act){
        float s = 0.f;
        #pragma unroll
        for (int h = 0; h < 64; h++) s += __expf(fmaf(kg, ybS[h], csS[tau][h]));
        U = __logf(s) - qg;
      }
      __syncthreads();
      if (act) csS[tau][lane] = lnng - qg - U;
      __syncthreads();
      if (act){
        float s = 0.f;
        #pragma unroll
        for (int h = 0; h < 64; h++) s += __expf(fmaf(kg, ybS[h], csS[tau][h]));
        V = __logf(s) - qg;
      }
      __syncthreads();
    }
    if (act){
      float C5 = lnng - qg - V;
      if (tau == 0) binA[lane] = make_float4(ybg, nfS[lane], C4, C5);
      else          binB[lane] = make_float2(C4, C5);
    }
  }

  // ---- rbf coeffs (wave-per-proto) + linear (wave-dot, 64 i's/wave) ----
  {
    float xv[16];
    #pragma unroll
    for (int k = 0; k < 4; k++){
      float4 a = ((float4*)xs)[lane + 64*k];
      xv[4*k+0]=a.x; xv[4*k+1]=a.y; xv[4*k+2]=a.z; xv[4*k+3]=a.w;
    }
    for (int p = wid; p < 32; p += 4){
      const float4* pr = (const float4*)(proto + p*DD);
      float s = 0.f;
      #pragma unroll
      for (int k = 0; k < 4; k++){
        float4 q = pr[lane + 64*k];
        float d0=xv[4*k+0]-q.x, d1=xv[4*k+1]-q.y;
        float d2=xv[4*k+2]-q.z, d3=xv[4*k+3]-q.w;
        s += d0*d0 + d1*d1 + d2*d2 + d3*d3;
      }
      s = wred_sum(s);
      if (lane == 0){
        coeff[p] = w_s[32]*__expf(-s*2.0f) + w_s[33]*__expf(-s*0.5f)
                 + w_s[34]*__expf(-s*0.125f);
      }
    }
    for (int t = 0; t < 64; t++){
      int i = qc*256 + wid*64 + t;
      const float4* Wr = (const float4*)(W + (size_t)i*DD);
      float s = 0.f;
      #pragma unroll
      for (int k = 0; k < 4; k++){
        float4 a = Wr[lane + 64*k];
        s = fmaf(a.x, xv[4*k+0], s); s = fmaf(a.y, xv[4*k+1], s);
        s = fmaf(a.z, xv[4*k+2], s); s = fmaf(a.w, xv[4*k+3], s);
      }
      s = wred_sum(s);
      if (lane == 0) linS[wid*64 + t] = s;
    }
  }
  __syncthreads();

  // ---- per-thread finale: elem + rbf-proj + binned attn/apply + store ----
  int i = qc*256 + tid;
  const float* w = w_s;
  float c = xs[i];
  float l = xs[i > 0 ? i-1 : 0];
  float r = xs[i < DD-1 ? i+1 : DD-1];
  float lap = l - 2.f*c + r;
  float s = 0.f;
  s += w[0]*__sinf(0.5f*c) + w[1]*__sinf(c) + w[2]*__sinf(2.f*c) + w[3]*__sinf(4.f*c);
  s += w[4]*__cosf(0.5f*c) + w[5]*__cosf(c) + w[6]*__cosf(2.f*c) + w[7]*__cosf(4.f*c);
  {
    float inner = 0.7978845608028654f * (c + 0.044715f*c*c*c);
    s += w[8] * 0.5f*c*(1.f + tanhf(inner));
    s += w[9] * tanhf(c);
    s += w[10] * (1.f / (1.f + __expf(-c)));
  }
  { float c2 = c*c; s += w[11]*c2 + w[12]*c2*c + w[13]*c2*c2; }
  {
    float ac = fabsf(c);
    s += w[14]*(c/(1.001f + 0.5f*ac)) + w[15]*(c/(1.001f + ac)) + w[16]*(c/(1.001f + 2.f*ac));
  }
  s += w[17]*(c + 0.001f*lap) + w[18]*(c + 0.003f*lap)
     + w[19]*(c + 0.01f*lap)  + w[20]*(c + 0.03f*lap);
  {
    float acc = w[21] * 0.786572f * c;
    {
      const float k1 = 0.106452f, k2 = 2.63876e-4f;
      float s1 = 0.f;
      s1 += k1 * ((i>=1 ? xs[i-1]:0.f) + (i<DD-1 ? xs[i+1]:0.f));
      s1 += k2 * ((i>=2 ? xs[i-2]:0.f) + (i<DD-2 ? xs[i+2]:0.f));
      acc += w[21] * s1;
    }
    {
      const float t1 = 0.242036f, t2 = 0.0540056f, t3 = 0.00443305f;
      float s1 = 0.399050f * c;
      s1 += t1 * ((i>=1 ? xs[i-1]:0.f) + (i<DD-1 ? xs[i+1]:0.f));
      s1 += t2 * ((i>=2 ? xs[i-2]:0.f) + (i<DD-2 ? xs[i+2]:0.f));
      s1 += t3 * ((i>=3 ? xs[i-3]:0.f) + (i<DD-3 ? xs[i+3]:0.f));
      acc += w[22] * s1;
    }
    {
      const float gk[7] = {0.199676f, 0.176216f, 0.121100f, 0.064825f,
                           0.027023f, 0.0087731f, 0.0022182f};
      float s1 = gk[0] * c;
      #pragma unroll
      for (int t = 1; t <= 6; t++)
        s1 += gk[t] * ((i>=t ? xs[i-t]:0.f) + (i<DD-t ? xs[i+t]:0.f));
      acc += w[23] * s1;
    }
    s += acc;
  }
  {
    const float taus[4] = {0.5f, 1.f, 2.f, 4.f};
    float m3 = fmaxf(l, fmaxf(c, r));
    #pragma unroll
    for (int ti = 0; ti < 4; ti++){
      float invt = 1.f / taus[ti];
      float e = __expf((l-m3)*invt) + __expf((c-m3)*invt) + __expf((r-m3)*invt);
      s += w[24 + ti] * (m3 + taus[ti]*__logf(e));
    }
  }
  {
    const float taus[4] = {0.5f, 1.f, 2.f, 4.f};
    float dl = fabsf(l - c), dr = fabsf(r - c);
    #pragma unroll
    for (int ti = 0; ti < 4; ti++){
      float invt = 1.f / taus[ti];
      float wl = __expf(-dl*invt), wr = __expf(-dr*invt);
      s += w[28 + ti] * ((wl*l + c + wr*r) / (wl + 1.f + wr));
    }
  }
  // rbf projection
  float rb = 0.f;
  #pragma unroll
  for (int p = 0; p < 32; p++) rb = fmaf(coeff[p], proj[p*DD + i], rb);
  // binned attention + sinkhorn apply (lane = i, bins as LDS broadcasts)
  float xi = c;
  float a1 = qk * 0.35355339059327373f * xi;
  float m1 = (a1 >= 0.f) ? a1*MX : a1*MN;
  float k0 = 4.f*xi, k1 = 2.f*xi;
  float s40=0.f, s50=0.f, s41=0.f, s51=0.f;
  float s1=0.f, sx1=0.f, s2=0.f, sx2=0.f;
  #pragma unroll 8
  for (int h = 0; h < 64; h++){
    float4 A  = binA[h];
    float2 Bv = binB[h];
    float yb = A.x, nf = A.y;
    s40 += __expf(fmaf(k0, yb, A.z));
    s50  = fmaf(__expf(fmaf(k0, yb, A.w)), yb, s50);
    s41 += __expf(fmaf(k1, yb, Bv.x));
    s51  = fmaf(__expf(fmaf(k1, yb, Bv.y)), yb, s51);
    float f  = __expf(fmaf(a1, yb, -m1));
    float f2 = f*f;
    s1 = fmaf(nf, f, s1);   sx1 = fmaf(nf*f, yb, sx1);
    s2 = fmaf(nf, f2, s2);  sx2 = fmaf(nf*f2, yb, sx2);
  }
  float sink = w[37]*(s50/s40) + w[38]*(s51/s41);
  float attn = vo*(w[35]*(sx2/s2) + w[36]*(sx1/s1));
  float lin  = linS[tid];
  out[b*DD + i] = xi + GAMMA_C*(s + w[39]*(lin + bl[i]) + rb + sink + attn);
}

extern "C" void kernel_launch(void* const* d_in, const int* in_sizes, int n_in,
                              void* d_out, int out_size, void* d_ws, size_t ws_size,
                              hipStream_t stream){
  const float* x     = (const float*)d_in[0];
  const float* beta  = (const float*)d_in[1];
  const float* W     = (const float*)d_in[2];
  const float* bl    = (const float*)d_in[3];
  const float* wq    = (const float*)d_in[4];
  const float* wk    = (const float*)d_in[5];
  const float* wv    = (const float*)d_in[6];
  const float* wo    = (const float*)d_in[7];
  const float* proto = (const float*)d_in[8];
  const float* proj  = (const float*)d_in[9];
  float* out = (float*)d_out;

  mega<<<BB*4, 256, 0, stream>>>(x, beta, W, bl, proj, wq, wk, wv, wo, proto, out);
}